// Round 3
// baseline (330.476 us; speedup 1.0000x reference)
//
#include <hip/hip_runtime.h>
#include <cstdint>

// ---------------------------------------------------------------------------
// AttentionModel: out = softmax((xWq^T+bq)(xWk^T+bk)^T / 32) (xWv^T+bv)
// B=4, S=2048, E=1024, fp32 in/out.  bf16 MFMA pipeline.
// R11: faithful m201 geometry.  R10 failed (MfmaUtil 23%) because per-wave
// 64x64 output needs 16 ds_read_b128 per 32 MFMA -> phase-lockstep serializes
// LDS(512cyc) + MFMA(307cyc) per K-tile at 1 blk/CU.  m201's per-wave 128x64
// (M_rep=8) does 24 reads per 64 MFMA -> 62% measured.  Now: BM=256, 8 waves
// (2Mx4N), per-wave 128x(BN/4), dbuf LDS, PH phases x 16 MFMA.  A staged in
// phase-aligned 32-row chunks; issue order [B*,A0 | A1 | A2 | A3] gives every
// load >=4 phases of latency cover; counted per-phase vmcnt {7,7,7,3} (BN=256)
// / {4,2} (BN=128), vmcnt(0) only in the last K-tile.
// Shapes: proj fused as ONE GEMM (B=[Wq;Wk;Wv], N=3072) 256x128 -> grid 32x24
// (768 blocks); scores 256x256 -> 256 blocks; PV 256x128 -> 256 blocks.
// Kept: XOR granule swizzle (0 conflicts), width-16 global_load_lds, 8x8
// super-tile block swizzle, fused epilogues, m89-verified C/D layout.
// ---------------------------------------------------------------------------

typedef __attribute__((ext_vector_type(8))) short bf16x8;
typedef __attribute__((ext_vector_type(4))) float f32x4;

__device__ __forceinline__ unsigned short f2bf(float f) {
  union { float f; uint32_t u; } x; x.f = f;
  uint32_t u = x.u;
  return (unsigned short)((u + 0x7fffu + ((u >> 16) & 1u)) >> 16);  // RNE
}

__device__ __forceinline__ void async_copy16(const void* g, void* l) {
  __builtin_amdgcn_global_load_lds(
      (const __attribute__((address_space(1))) void*)g,
      (__attribute__((address_space(3))) void*)l, 16, 0, 0);
}

#define FENCE() asm volatile("" ::: "memory")

__device__ __forceinline__ void wg_bar() {
  FENCE();
  __builtin_amdgcn_s_barrier();
  FENCE();
}

template <int N>
__device__ __forceinline__ void vm_wait() {
  if constexpr (N == 0)      asm volatile("s_waitcnt vmcnt(0)" ::: "memory");
  else if constexpr (N == 2) asm volatile("s_waitcnt vmcnt(2)" ::: "memory");
  else if constexpr (N == 3) asm volatile("s_waitcnt vmcnt(3)" ::: "memory");
  else if constexpr (N == 4) asm volatile("s_waitcnt vmcnt(4)" ::: "memory");
  else                       asm volatile("s_waitcnt vmcnt(7)" ::: "memory");
}

// ---------------------------------------------------------------------------
// Merged fp32->bf16 convert for x, Wq, Wk, Wv; last block zeroes rowsum.
// ---------------------------------------------------------------------------
__global__ __launch_bounds__(256) void convert_all(
    const float* __restrict__ x, const float* __restrict__ Wq,
    const float* __restrict__ Wk, const float* __restrict__ Wv,
    unsigned short* __restrict__ xb, unsigned short* __restrict__ Wb,
    float* __restrict__ rowsum) {
  const long X4 = (long)8192 * 1024 / 4;
  const long W4 = (long)1024 * 1024 / 4;
  if (blockIdx.x == gridDim.x - 1) {
    float4* r = (float4*)rowsum;
#pragma unroll
    for (int t = 0; t < 8; ++t)
      r[threadIdx.x + t * 256] = float4{0.f, 0.f, 0.f, 0.f};
    return;
  }
  long i = (long)blockIdx.x * 256 + threadIdx.x;
  const float* src; unsigned short* dst; long off;
  if (i < X4)             { src = x;  dst = xb;                    off = i; }
  else if (i < X4 + W4)   { src = Wq; dst = Wb;                    off = i - X4; }
  else if (i < X4 + 2*W4) { src = Wk; dst = Wb + (long)1024*1024;  off = i - X4 - W4; }
  else                    { src = Wv; dst = Wb + (long)2048*1024;  off = i - X4 - 2*W4; }
  const float4 v = ((const float4*)src)[off];
  ushort4 o;
  o.x = f2bf(v.x); o.y = f2bf(v.y); o.z = f2bf(v.z); o.w = f2bf(v.w);
  ((ushort4*)dst)[off] = o;
}

// ---------------------------------------------------------------------------
// C[M,N] = op( scale * (A[M,K] x B[N,K]^T) + bias )
// MODE 0 (PROJ fused): N=3072 = [Q|K|V] features; p = col>>10 selects proj;
//                      p<2 -> bf16 rows into Q/K; p==2 -> V transposed
// MODE 1 (SCORES): bf16 out = exp(scale*acc); atomicAdd per-row sums
// MODE 2 (PV):     fp32 out = acc * (1/rowsum[row])
// 512 threads = 8 waves (2M x 4N), BM=256 x BN tile, BK=64, per-wave 128x(BN/4)
// (M_rep=8).  dbuf LDS; PH = BN==256?4:2 phases x 16 MFMA; counted vmcnt.
// ---------------------------------------------------------------------------
template <int MODE, int BN>
__global__ __launch_bounds__(512, 2) void gemm_bt(
    const unsigned short* __restrict__ Ab, const unsigned short* __restrict__ Bb,
    unsigned short* __restrict__ Cb, float* __restrict__ Cf,
    unsigned short* __restrict__ VT,
    const float* __restrict__ bias0, const float* __restrict__ bias1,
    const float* __restrict__ bias2, float* __restrict__ rowsum,
    int K, int N, float scale, long sA, long sB, long sC) {
  constexpr int BM    = 256;
  constexpr int N_rep = BN / 64;            // 4 or 2
  constexpr int PH    = (BN == 256) ? 4 : 2;
  constexpr int MF    = 8 / PH;             // m-frags per phase: 2 or 4
  constexpr int NB    = BN / 64;            // B stage-loads per thread

  __shared__ unsigned short As[2][BM * 64];
  __shared__ unsigned short Bs[2][BN * 64];

  const int z = blockIdx.z;
  const unsigned short* A  = Ab + (long)z * sA;
  const unsigned short* Bm = Bb + (long)z * sB;

  const int tid  = threadIdx.x;
  const int lane = tid & 63;
  const int wave = tid >> 6;
  const int l15  = lane & 15;
  const int quad = lane >> 4;
  const int wn   = wave & 3;          // 4 column waves
  const int wm   = wave >> 2;         // 2 row waves
  const int wmr  = wm * 128;          // wave row base (per-wave 128 rows)
  const int wnc  = wn * (BN / 4);     // wave col base (per-wave BN/4 cols)

  // --- 8x8 super-tile swizzle for L2 locality ---
  const int bxd  = gridDim.x;
  const int flat = blockIdx.y * bxd + blockIdx.x;
  const int st = flat >> 6;
  const int inside = flat & 63;
  const int nstx = bxd >> 3;
  const int stx = st % nstx;
  const int sty = st / nstx;
  const int tile_m = (stx * 8 + (inside & 7)) * BM;
  const int tile_n = (sty * 8 + (inside >> 3)) * BN;

  // --- staging map.  A chunk t (t=0..3) = rows [h*128 + t*32, +32),
  // h = wave>>2; within a chunk wave q=wave&3 covers rows q*8..q*8+7.
  // B chunk t (t=0..NB-1) = rows [t*64, +64); wave covers rows wave*8..+8.
  // Lane L -> row +(L>>3), LDS granule L&7, global k-chunk (L&7)^(L>>3)
  // (XOR granule swizzle; physical granule g of row r holds chunk g^(r&7)).
  const int rs8 = lane >> 3;
  const int kc  = (lane & 7) ^ rs8;
  const long lK = (long)K;
  const int aRow0 = (wave >> 2) * 128 + (wave & 3) * 8;   // + t*32
  const int bRow0 = wave * 8;                             // + t*64
  const unsigned short* gA0 = A  + (long)(tile_m + aRow0 + rs8) * lK + kc * 8;
  const unsigned short* gB0 = Bm + (long)(tile_n + bRow0 + rs8) * lK + kc * 8;

  auto stageA = [&](int t, int k0, int pb) {
    async_copy16(gA0 + (long)(t * 32) * lK + k0, &As[pb][(aRow0 + t * 32) * 64]);
  };
  auto stageB = [&](int t, int k0, int pb) {
    async_copy16(gB0 + (long)(t * 64) * lK + k0, &Bs[pb][(bRow0 + t * 64) * 64]);
  };

  const int NT = K >> 6;
  f32x4 acc[8][N_rep] = {};

  // prologue: stage tile 0 in canonical order [B0..B_{NB-1}, A0..A3];
  // wait B* + A0 (+A1 for PH==2) landed, leave the rest in flight.
#pragma unroll
  for (int tb = 0; tb < NB; ++tb) stageB(tb, 0, 0);
#pragma unroll
  for (int ta = 0; ta < 4; ++ta) stageA(ta, 0, 0);
  if constexpr (PH == 4) vm_wait<3>(); else vm_wait<2>();
  wg_bar();

  int p = 0;
  for (int t = 0; t < NT; ++t) {
    const int q = p ^ 1;
    const bool more = (t + 1 < NT);
    const int k1 = (t + 1) << 6;
    const unsigned short* as = &As[p][0];
    const unsigned short* bs = &Bs[p][0];
    bf16x8 bfr[N_rep][2];
#pragma unroll
    for (int ph = 0; ph < PH; ++ph) {
      // --- stage-issue chunk set for tile t+1 (buf q) ---
      if (more) {
        if (ph == 0) {
#pragma unroll
          for (int tb = 0; tb < NB; ++tb) stageB(tb, k1, q);
          stageA(0, k1, q);
          if constexpr (PH == 2) stageA(1, k1, q);
        } else {
          if constexpr (PH == 4) {
            stageA(ph, k1, q);
          } else {
            stageA(2, k1, q);
            stageA(3, k1, q);
          }
        }
      }
      // --- ds_read fragments for this phase (buf p) ---
      bf16x8 af[MF][2];
#pragma unroll
      for (int ii = 0; ii < MF; ++ii) {
        const int row = wmr + (ph * MF + ii) * 16 + l15;
#pragma unroll
        for (int kk = 0; kk < 2; ++kk)
          af[ii][kk] = *(const bf16x8*)&as[row * 64 + (((kk * 4 + quad) ^ (l15 & 7)) << 3)];
      }
      if (ph == 0) {  // B frags resident for the whole K-tile
#pragma unroll
        for (int j = 0; j < N_rep; ++j) {
          const int row = wnc + j * 16 + l15;
#pragma unroll
          for (int kk = 0; kk < 2; ++kk)
            bfr[j][kk] = *(const bf16x8*)&bs[row * 64 + (((kk * 4 + quad) ^ (l15 & 7)) << 3)];
        }
      }
      wg_bar();                       // all waves enter MFMA cluster together
      __builtin_amdgcn_s_setprio(1);
#pragma unroll
      for (int ii = 0; ii < MF; ++ii)
#pragma unroll
        for (int j = 0; j < N_rep; ++j)
#pragma unroll
          for (int kk = 0; kk < 2; ++kk)
            acc[ph * MF + ii][j] = __builtin_amdgcn_mfma_f32_16x16x32_bf16(
                af[ii][kk], bfr[j][kk], acc[ph * MF + ii][j], 0, 0, 0);
      __builtin_amdgcn_s_setprio(0);
      // --- counted wait: confirm exactly the chunks the next phase reads ---
      if (more) {
        if constexpr (PH == 4) { if (ph < 3) vm_wait<7>(); else vm_wait<3>(); }
        else                   { if (ph == 0) vm_wait<4>(); else vm_wait<2>(); }
      } else {
        vm_wait<0>();
      }
      wg_bar();
    }
    p ^= 1;
  }

  // ------------------------- epilogue -------------------------
  // C/D layout: col = lane&15, row = quad*4 + reg (m89-verified)
  if constexpr (MODE == 0) {
    const int proj  = tile_n >> 10;      // block-uniform (BN=128 divides 1024)
    const int fbase = (tile_n & 1023);
    if (proj == 2) {
      // write V transposed: VT[b][f][s], b = row>>11, s = row&2047
#pragma unroll
      for (int j = 0; j < N_rep; ++j) {
        const int f = fbase + wnc + j * 16 + l15;  // feature
        const float bv = bias2[f];
#pragma unroll
        for (int i = 0; i < 8; ++i) {
          const int row0 = tile_m + wmr + i * 16 + quad * 4;  // token
          const int b = row0 >> 11;
          const int sx = row0 & 2047;
          ushort4 o;
          o.x = f2bf(acc[i][j][0] + bv);
          o.y = f2bf(acc[i][j][1] + bv);
          o.z = f2bf(acc[i][j][2] + bv);
          o.w = f2bf(acc[i][j][3] + bv);
          *(ushort4*)&VT[(long)b * 1024 * 2048 + (long)f * 2048 + sx] = o;
        }
      }
    } else {
      const float* bias = proj ? bias1 : bias0;
      unsigned short* dst = Cb + (long)proj * (8192L * 1024);
#pragma unroll
      for (int j = 0; j < N_rep; ++j) {
        const int f = fbase + wnc + j * 16 + l15;
        const float bv = bias[f];
#pragma unroll
        for (int i = 0; i < 8; ++i) {
          const int row0 = tile_m + wmr + i * 16 + quad * 4;
#pragma unroll
          for (int r = 0; r < 4; ++r)
            dst[(long)(row0 + r) * 1024 + f] = f2bf(acc[i][j][r] + bv);
        }
      }
    }
  } else if constexpr (MODE == 1) {
    // exp epilogue + row-sum atomics
    unsigned short* Cbz = Cb + (long)z * sC;
    float part[32];
#pragma unroll
    for (int t = 0; t < 32; ++t) part[t] = 0.0f;
#pragma unroll
    for (int j = 0; j < N_rep; ++j) {
      const int col = tile_n + wnc + j * 16 + l15;
#pragma unroll
      for (int i = 0; i < 8; ++i) {
        const int row0 = tile_m + wmr + i * 16 + quad * 4;
#pragma unroll
        for (int r = 0; r < 4; ++r) {
          const float e = __expf(acc[i][j][r] * scale);
          part[i * 4 + r] += e;
          Cbz[(long)(row0 + r) * N + col] = f2bf(e);
        }
      }
    }
    // reduce across the 16 lanes (l15) sharing each row
#pragma unroll
    for (int t = 0; t < 32; ++t)
#pragma unroll
      for (int o = 1; o < 16; o <<= 1)
        part[t] += __shfl_xor(part[t], o);
    if (l15 == 0) {
#pragma unroll
      for (int i = 0; i < 8; ++i) {
        const int row0 = tile_m + wmr + i * 16 + quad * 4;
#pragma unroll
        for (int r = 0; r < 4; ++r)
          atomicAdd(&rowsum[z * 2048 + row0 + r], part[i * 4 + r]);
      }
    }
  } else {
    // PV: normalize by rowsum
    float* Cfz = Cf + (long)z * sC;
    float inv[32];
#pragma unroll
    for (int i = 0; i < 8; ++i) {
      const int row0 = tile_m + wmr + i * 16 + quad * 4;
#pragma unroll
      for (int r = 0; r < 4; ++r)
        inv[i * 4 + r] = 1.0f / rowsum[z * 2048 + row0 + r];
    }
#pragma unroll
    for (int j = 0; j < N_rep; ++j) {
      const int col = tile_n + wnc + j * 16 + l15;
#pragma unroll
      for (int i = 0; i < 8; ++i) {
        const int row0 = tile_m + wmr + i * 16 + quad * 4;
#pragma unroll
        for (int r = 0; r < 4; ++r)
          Cfz[(long)(row0 + r) * N + col] = acc[i][j][r] * inv[i * 4 + r];
      }
    }
  }
}

// ---------------------------------------------------------------------------
extern "C" void kernel_launch(void* const* d_in, const int* in_sizes, int n_in,
                              void* d_out, int out_size, void* d_ws, size_t ws_size,
                              hipStream_t stream) {
  const float* x  = (const float*)d_in[0];
  const float* Wq = (const float*)d_in[1];
  const float* bq = (const float*)d_in[2];
  const float* Wk = (const float*)d_in[3];
  const float* bk = (const float*)d_in[4];
  const float* Wv = (const float*)d_in[5];
  const float* bv = (const float*)d_in[6];
  float* out = (float*)d_out;

  constexpr int Bt = 4, S = 2048, E = 1024;
  constexpr int M = Bt * S;  // 8192

  // ws layout (bf16): x_bf | W_bf(3) | Q | K | VT | P(exp scores) | rowsum(f32)
  unsigned short* xb = (unsigned short*)d_ws;
  unsigned short* Wb = xb + (size_t)M * E;
  unsigned short* Q  = Wb + (size_t)3 * E * E;
  unsigned short* Kb = Q + (size_t)M * E;      // contiguous after Q
  unsigned short* VT = Kb + (size_t)M * E;
  unsigned short* P  = VT + (size_t)M * E;
  float* rowsum = (float*)(P + (size_t)Bt * S * S);

  // 1) converts + rowsum zeroing (one launch)
  const int conv_blocks = (M * E / 4 + 3 * (E * E / 4)) / 256 + 1;
  convert_all<<<dim3(conv_blocks), dim3(256), 0, stream>>>(x, Wq, Wk, Wv, xb, Wb, rowsum);

  // 2) projections fused: C[8192, 3072] = x (Wqkv)^T; Q/K rows, V transposed
  //    256x128 tile -> grid 32x24 = 768 blocks
  gemm_bt<0, 128><<<dim3(M / 256, 3072 / 128, 1), dim3(512), 0, stream>>>(
      xb, Wb, Q, nullptr, VT, bq, bk, bv, nullptr, E, E, 1.0f,
      0L, 0L, 0L);

  // 3) P = exp(Q K^T / 32) (unnormalized) + row sums
  //    256x256 tile -> grid 8x8x4 = 256 blocks
  gemm_bt<1, 256><<<dim3(S / 256, S / 256, Bt), dim3(512), 0, stream>>>(
      Q, Kb, P, nullptr, nullptr, nullptr, nullptr, nullptr, rowsum,
      E, S, 1.0f / 32.0f, (long)S * E, (long)S * E, (long)S * S);

  // 4) out = (P V) / rowsum   (fp32 out)
  //    256x128 tile -> grid 8x8x4 = 256 blocks
  gemm_bt<2, 128><<<dim3(S / 256, E / 128, Bt), dim3(512), 0, stream>>>(
      P, VT, nullptr, out, nullptr, nullptr, nullptr, nullptr, rowsum,
      S, E, 1.0f, (long)S * S, (long)E * S, (long)S * E);
}

// Round 4
// 290.206 us; speedup vs baseline: 1.1388x; 1.1388x over previous
//
#include <hip/hip_runtime.h>
#include <cstdint>

// ---------------------------------------------------------------------------
// AttentionModel: out = softmax((xWq^T+bq)(xWk^T+bk)^T / 32) (xWv^T+bv)
// B=4, S=2048, E=1024, fp32 in/out.  bf16 MFMA pipeline.
// R12 = R8 structure (verified 236us: 4 waves, 128x128 tile, 4 blocks/CU,
// cross-block TLP is the overlap mechanism) + ONE change: MFMA shape
// 16x16x32 -> 32x32x16.  Halves LDS fragment traffic per FLOP (per K-tile
// per block: 96KB->64KB ds_read vs ~600cyc matrix) and uses the faster
// 32x32 pipe (2382 vs 2075 TF ubench).  acc = 2x2 x f32x16 = 64 AGPR (same
// budget as R8 -> occupancy unchanged at 4 blocks/CU).
// R9-R11 lesson: 8-wave lockstep phase schedules all landed 18-23% util
// (every stall is global at 1 block/CU); R8's 37% came from 4 independent
// blocks interleaving.  Keep that mechanism.
// Kept verbatim: staging map + XOR granule swizzle (0 conflicts), width-16
// global_load_lds, 8x8 super-tile swizzle, fused epilogues, launches.
// 32x32 C/D layout (m74/m101): col = lane&31, row = (r&3)+8*(r>>2)+4*(lane>>5).
// A/B frags: row/col = lane&31, k = 8*(lane>>5)+elem (doubling of the proven
// 16x16x32 mapping).
// ---------------------------------------------------------------------------

typedef __attribute__((ext_vector_type(8))) short bf16x8;
typedef __attribute__((ext_vector_type(16))) float f32x16;

__device__ __forceinline__ unsigned short f2bf(float f) {
  union { float f; uint32_t u; } x; x.f = f;
  uint32_t u = x.u;
  return (unsigned short)((u + 0x7fffu + ((u >> 16) & 1u)) >> 16);  // RNE
}

__device__ __forceinline__ void async_copy16(const void* g, void* l) {
  __builtin_amdgcn_global_load_lds(
      (const __attribute__((address_space(1))) void*)g,
      (__attribute__((address_space(3))) void*)l, 16, 0, 0);
}

// ---------------------------------------------------------------------------
// Merged fp32->bf16 convert for x, Wq, Wk, Wv; last block zeroes rowsum.
// ---------------------------------------------------------------------------
__global__ __launch_bounds__(256) void convert_all(
    const float* __restrict__ x, const float* __restrict__ Wq,
    const float* __restrict__ Wk, const float* __restrict__ Wv,
    unsigned short* __restrict__ xb, unsigned short* __restrict__ Wb,
    float* __restrict__ rowsum) {
  const long X4 = (long)8192 * 1024 / 4;
  const long W4 = (long)1024 * 1024 / 4;
  if (blockIdx.x == gridDim.x - 1) {
    float4* r = (float4*)rowsum;
#pragma unroll
    for (int t = 0; t < 8; ++t)
      r[threadIdx.x + t * 256] = float4{0.f, 0.f, 0.f, 0.f};
    return;
  }
  long i = (long)blockIdx.x * 256 + threadIdx.x;
  const float* src; unsigned short* dst; long off;
  if (i < X4)             { src = x;  dst = xb;                    off = i; }
  else if (i < X4 + W4)   { src = Wq; dst = Wb;                    off = i - X4; }
  else if (i < X4 + 2*W4) { src = Wk; dst = Wb + (long)1024*1024;  off = i - X4 - W4; }
  else                    { src = Wv; dst = Wb + (long)2048*1024;  off = i - X4 - 2*W4; }
  const float4 v = ((const float4*)src)[off];
  ushort4 o;
  o.x = f2bf(v.x); o.y = f2bf(v.y); o.z = f2bf(v.z); o.w = f2bf(v.w);
  ((ushort4*)dst)[off] = o;
}

// ---------------------------------------------------------------------------
// C[M,N] = op( scale * (A[M,K] x B[N,K]^T) + bias )
// MODE 0 (PROJ):   bf16 out; z<2 -> normal rows; z==2 -> write V transposed
// MODE 1 (SCORES): bf16 out = exp(scale*acc); atomicAdd per-row sums
// MODE 2 (PV):     fp32 out = acc * (1/rowsum[row])
// 256 threads = 4 waves, 128x128 tile, BK=64, 32x32x16 bf16 MFMA.
// Block swizzle: flat id -> 8x8 super-tiles (requires grid dims % 8 == 0).
// ---------------------------------------------------------------------------
template <int MODE>
__global__ __launch_bounds__(256, 4) void gemm_bt(
    const unsigned short* __restrict__ Ab, const unsigned short* __restrict__ Bb,
    unsigned short* __restrict__ Cb, float* __restrict__ Cf,
    unsigned short* __restrict__ VT,
    const float* __restrict__ bias0, const float* __restrict__ bias1,
    const float* __restrict__ bias2, float* __restrict__ rowsum,
    int K, int N, float scale, long sA, long sB, long sC) {
  __shared__ unsigned short As[128 * 64];
  __shared__ unsigned short Bs[128 * 64];

  const int z = blockIdx.z;
  const unsigned short* A  = Ab + (long)z * sA;
  const unsigned short* Bm = Bb + (long)z * sB;

  const int tid  = threadIdx.x;
  const int lane = tid & 63;
  const int wave = tid >> 6;
  const int l31  = lane & 31;
  const int h5   = lane >> 5;
  const int l7   = lane & 7;
  const int wm = (wave >> 1) * 64;
  const int wn = (wave & 1) * 64;

  // --- 8x8 super-tile swizzle for L2 locality ---
  const int bxd  = gridDim.x;
  const int flat = blockIdx.y * bxd + blockIdx.x;
  const int st = flat >> 6;          // super-tile index (64 blocks each)
  const int inside = flat & 63;
  const int nstx = bxd >> 3;
  const int stx = st % nstx;
  const int sty = st / nstx;
  const int tile_m = (stx * 8 + (inside & 7)) * 128;
  const int tile_n = (sty * 8 + (inside >> 3)) * 128;

  // --- staging map: wave w covers rows [w*32, w*32+32), 4 instrs x 8 rows.
  // Lane L -> LDS slot L&7 of row strip+(L>>3); content = chunk (L&7)^(L>>3).
  const int rs8 = lane >> 3;
  const int kc  = (lane & 7) ^ rs8;
  const long lK = (long)K;
  const unsigned short* gA0 = A  + (long)(tile_m + wave * 32 + rs8) * lK + kc * 8;
  const unsigned short* gB0 = Bm + (long)(tile_n + wave * 32 + rs8) * lK + kc * 8;
  unsigned short* lA = &As[(wave * 32) * 64];
  unsigned short* lB = &Bs[(wave * 32) * 64];

  f32x16 acc[2][2] = {};

  for (int k0 = 0; k0 < K; k0 += 64) {
    __syncthreads();  // previous-iter LDS readers done
#pragma unroll
    for (int t = 0; t < 4; ++t) {
      async_copy16(gA0 + (long)t * 8 * lK + k0, lA + t * 8 * 64);
      async_copy16(gB0 + (long)t * 8 * lK + k0, lB + t * 8 * 64);
    }
    __syncthreads();  // drain: LDS tile ready

    // K-tile = 4 slabs of K=16; process 2 slabs per batch (mirrors R8).
    // Fragment: row/col = base + l31, logical 8-elem chunk = slab*2 + h5,
    // physical granule = chunk ^ (row&7) = chunk ^ l7.
#pragma unroll
    for (int s2 = 0; s2 < 2; ++s2) {
      bf16x8 af[2][2], bfr[2][2];
#pragma unroll
      for (int ss = 0; ss < 2; ++ss) {
        const int ch = ((s2 * 2 + ss) * 2 + h5) ^ l7;
#pragma unroll
        for (int i = 0; i < 2; ++i) {
          af[i][ss]  = *(const bf16x8*)&As[(wm + i * 32 + l31) * 64 + (ch << 3)];
          bfr[i][ss] = *(const bf16x8*)&Bs[(wn + i * 32 + l31) * 64 + (ch << 3)];
        }
      }
#pragma unroll
      for (int ss = 0; ss < 2; ++ss)
#pragma unroll
        for (int i = 0; i < 2; ++i)
#pragma unroll
          for (int j = 0; j < 2; ++j)
            acc[i][j] = __builtin_amdgcn_mfma_f32_32x32x16_bf16(
                af[i][ss], bfr[j][ss], acc[i][j], 0, 0, 0);
    }
  }

  // ------------------------- epilogue -------------------------
  // C/D layout (m74/m101): col = lane&31, row = (r&3) + 8*(r>>2) + 4*h5
  if constexpr (MODE == 0) {
    const float* bias = (z == 0) ? bias0 : (z == 1) ? bias1 : bias2;
    if (z == 2) {
      // write V transposed: VT[b][f][s], b = row>>11, s = row&2047
#pragma unroll
      for (int j = 0; j < 2; ++j) {
        const int f = tile_n + wn + j * 32 + l31;  // feature
        const float bv = bias[f];
#pragma unroll
        for (int i = 0; i < 2; ++i) {
#pragma unroll
          for (int q = 0; q < 4; ++q) {
            const int row0 = tile_m + wm + i * 32 + q * 8 + h5 * 4;  // token
            const int b = row0 >> 11;
            const int sx = row0 & 2047;
            ushort4 o;
            o.x = f2bf(acc[i][j][q * 4 + 0] + bv);
            o.y = f2bf(acc[i][j][q * 4 + 1] + bv);
            o.z = f2bf(acc[i][j][q * 4 + 2] + bv);
            o.w = f2bf(acc[i][j][q * 4 + 3] + bv);
            *(ushort4*)&VT[(long)b * 1024 * 2048 + (long)f * 2048 + sx] = o;
          }
        }
      }
    } else {
      unsigned short* Cbz = Cb + (long)z * sC;
#pragma unroll
      for (int j = 0; j < 2; ++j) {
        const int col = tile_n + wn + j * 32 + l31;
        const float bv = bias[col];
#pragma unroll
        for (int i = 0; i < 2; ++i) {
          const int rbase = tile_m + wm + i * 32 + h5 * 4;
#pragma unroll
          for (int q = 0; q < 4; ++q)
#pragma unroll
            for (int rr = 0; rr < 4; ++rr)
              Cbz[(long)(rbase + q * 8 + rr) * N + col] =
                  f2bf(acc[i][j][q * 4 + rr] + bv);
        }
      }
    }
  } else if constexpr (MODE == 1) {
    // exp epilogue + row-sum atomics
    unsigned short* Cbz = Cb + (long)z * sC;
    float part[32];
#pragma unroll
    for (int t = 0; t < 32; ++t) part[t] = 0.0f;
#pragma unroll
    for (int j = 0; j < 2; ++j) {
      const int col = tile_n + wn + j * 32 + l31;
#pragma unroll
      for (int i = 0; i < 2; ++i) {
        const int rbase = tile_m + wm + i * 32 + h5 * 4;
#pragma unroll
        for (int q = 0; q < 4; ++q)
#pragma unroll
          for (int rr = 0; rr < 4; ++rr) {
            const float e = __expf(acc[i][j][q * 4 + rr] * scale);
            part[i * 16 + q * 4 + rr] += e;
            Cbz[(long)(rbase + q * 8 + rr) * N + col] = f2bf(e);
          }
      }
    }
    // reduce across the 32 lanes (l31) sharing each row (same h5 half)
#pragma unroll
    for (int t = 0; t < 32; ++t)
#pragma unroll
      for (int o = 1; o < 32; o <<= 1)
        part[t] += __shfl_xor(part[t], o);
    if (l31 == 0) {  // lanes 0 and 32 write disjoint row sets
#pragma unroll
      for (int i = 0; i < 2; ++i) {
        const int rbase = tile_m + wm + i * 32 + h5 * 4;
#pragma unroll
        for (int q = 0; q < 4; ++q)
#pragma unroll
          for (int rr = 0; rr < 4; ++rr)
            atomicAdd(&rowsum[z * 2048 + rbase + q * 8 + rr],
                      part[i * 16 + q * 4 + rr]);
      }
    }
  } else {
    // PV: normalize by rowsum
    float* Cfz = Cf + (long)z * sC;
    float inv[32];
#pragma unroll
    for (int i = 0; i < 2; ++i) {
      const int rbase = tile_m + wm + i * 32 + h5 * 4;
#pragma unroll
      for (int q = 0; q < 4; ++q)
#pragma unroll
        for (int rr = 0; rr < 4; ++rr)
          inv[i * 16 + q * 4 + rr] = 1.0f / rowsum[z * 2048 + rbase + q * 8 + rr];
    }
#pragma unroll
    for (int j = 0; j < 2; ++j) {
      const int col = tile_n + wn + j * 32 + l31;
#pragma unroll
      for (int i = 0; i < 2; ++i) {
        const int rbase = tile_m + wm + i * 32 + h5 * 4;
#pragma unroll
        for (int q = 0; q < 4; ++q)
#pragma unroll
          for (int rr = 0; rr < 4; ++rr)
            Cfz[(long)(rbase + q * 8 + rr) * N + col] =
                acc[i][j][q * 4 + rr] * inv[i * 16 + q * 4 + rr];
      }
    }
  }
}

// ---------------------------------------------------------------------------
extern "C" void kernel_launch(void* const* d_in, const int* in_sizes, int n_in,
                              void* d_out, int out_size, void* d_ws, size_t ws_size,
                              hipStream_t stream) {
  const float* x  = (const float*)d_in[0];
  const float* Wq = (const float*)d_in[1];
  const float* bq = (const float*)d_in[2];
  const float* Wk = (const float*)d_in[3];
  const float* bk = (const float*)d_in[4];
  const float* Wv = (const float*)d_in[5];
  const float* bv = (const float*)d_in[6];
  float* out = (float*)d_out;

  constexpr int Bt = 4, S = 2048, E = 1024;
  constexpr int M = Bt * S;  // 8192

  // ws layout (bf16): x_bf | W_bf(3) | Q | K | VT | P(exp scores) | rowsum(f32)
  unsigned short* xb = (unsigned short*)d_ws;
  unsigned short* Wb = xb + (size_t)M * E;
  unsigned short* Q  = Wb + (size_t)3 * E * E;
  unsigned short* Kb = Q + (size_t)M * E;
  unsigned short* VT = Kb + (size_t)M * E;
  unsigned short* P  = VT + (size_t)M * E;
  float* rowsum = (float*)(P + (size_t)Bt * S * S);

  // 1) converts + rowsum zeroing (one launch)
  const int conv_blocks = (M * E / 4 + 3 * (E * E / 4)) / 256 + 1;
  convert_all<<<dim3(conv_blocks), dim3(256), 0, stream>>>(x, Wq, Wk, Wv, xb, Wb, rowsum);

  // 2) projections: z in {Q,K,V}; y = x W^T + b; V written transposed
  gemm_bt<0><<<dim3(M / 128, E / 128, 3), dim3(256), 0, stream>>>(
      xb, Wb, Q, nullptr, VT, bq, bk, bv, nullptr, E, E, 1.0f,
      0L, (long)E * E, (long)M * E);

  // 3) P = exp(Q K^T / 32) (unnormalized) + row sums
  gemm_bt<1><<<dim3(S / 128, S / 128, Bt), dim3(256), 0, stream>>>(
      Q, Kb, P, nullptr, nullptr, nullptr, nullptr, nullptr, rowsum,
      E, S, 1.0f / 32.0f, (long)S * E, (long)S * E, (long)S * S);

  // 4) out = (P V) / rowsum   (fp32 out)
  gemm_bt<2><<<dim3(S / 128, E / 128, Bt), dim3(256), 0, stream>>>(
      P, VT, nullptr, out, nullptr, nullptr, nullptr, nullptr, rowsum,
      S, E, 1.0f, (long)S * S, (long)E * S, (long)S * E);
}

// Round 5
// 263.109 us; speedup vs baseline: 1.2560x; 1.1030x over previous
//
#include <hip/hip_runtime.h>
#include <cstdint>

// ---------------------------------------------------------------------------
// AttentionModel: out = softmax((xWq^T+bq)(xWk^T+bk)^T / 32) (xWv^T+bv)
// B=4, S=2048, E=1024, fp32 in/out.  bf16 MFMA pipeline.
// R13: hedged.  proj/PV/convert = R8-verbatim (verified 236us best).
// scores = NEW half-tile-ring 8-phase kernel (m201-faithful):
//   256x256 tile, 8 waves, per-wave 256x32 (M-progressive A consumption),
//   dbuf LDS in HALF granules, stage 1 half/phase into regions freed by a
//   barrier (race-checked), ONE counted vm_wait<4> per K-tile (3.5-phase
//   landing cover), vmcnt(0) only at tail.  Grid 8x8x4 = 256 = 1 blk/CU.
// R12 lesson (logged): 32x32 MFMA frags at BK=64 row-layout are pigeonhole-
// forced into >=4-way LDS conflicts (4-6M measured).  16x16x32 only.
// ---------------------------------------------------------------------------

typedef __attribute__((ext_vector_type(8))) short bf16x8;
typedef __attribute__((ext_vector_type(4))) float f32x4;

__device__ __forceinline__ unsigned short f2bf(float f) {
  union { float f; uint32_t u; } x; x.f = f;
  uint32_t u = x.u;
  return (unsigned short)((u + 0x7fffu + ((u >> 16) & 1u)) >> 16);  // RNE
}

__device__ __forceinline__ void async_copy16(const void* g, void* l) {
  __builtin_amdgcn_global_load_lds(
      (const __attribute__((address_space(1))) void*)g,
      (__attribute__((address_space(3))) void*)l, 16, 0, 0);
}

#define FENCE() asm volatile("" ::: "memory")

__device__ __forceinline__ void wg_bar() {
  FENCE();
  __builtin_amdgcn_s_barrier();
  FENCE();
}

template <int N>
__device__ __forceinline__ void vm_wait() {
  if constexpr (N == 0)      asm volatile("s_waitcnt vmcnt(0)" ::: "memory");
  else if constexpr (N == 4) asm volatile("s_waitcnt vmcnt(4)" ::: "memory");
  else                       asm volatile("s_waitcnt vmcnt(8)" ::: "memory");
}

// ---------------------------------------------------------------------------
// Merged fp32->bf16 convert for x, Wq, Wk, Wv; last block zeroes rowsum.
// ---------------------------------------------------------------------------
__global__ __launch_bounds__(256) void convert_all(
    const float* __restrict__ x, const float* __restrict__ Wq,
    const float* __restrict__ Wk, const float* __restrict__ Wv,
    unsigned short* __restrict__ xb, unsigned short* __restrict__ Wb,
    float* __restrict__ rowsum) {
  const long X4 = (long)8192 * 1024 / 4;
  const long W4 = (long)1024 * 1024 / 4;
  if (blockIdx.x == gridDim.x - 1) {
    float4* r = (float4*)rowsum;
#pragma unroll
    for (int t = 0; t < 8; ++t)
      r[threadIdx.x + t * 256] = float4{0.f, 0.f, 0.f, 0.f};
    return;
  }
  long i = (long)blockIdx.x * 256 + threadIdx.x;
  const float* src; unsigned short* dst; long off;
  if (i < X4)             { src = x;  dst = xb;                    off = i; }
  else if (i < X4 + W4)   { src = Wq; dst = Wb;                    off = i - X4; }
  else if (i < X4 + 2*W4) { src = Wk; dst = Wb + (long)1024*1024;  off = i - X4 - W4; }
  else                    { src = Wv; dst = Wb + (long)2048*1024;  off = i - X4 - 2*W4; }
  const float4 v = ((const float4*)src)[off];
  ushort4 o;
  o.x = f2bf(v.x); o.y = f2bf(v.y); o.z = f2bf(v.z); o.w = f2bf(v.w);
  ((ushort4*)dst)[off] = o;
}

// ---------------------------------------------------------------------------
// R8 GEMM (verbatim): C[M,N] = op( scale * (A[M,K] x B[N,K]^T) + bias )
// MODE 0 (PROJ):   bf16 out; z<2 -> normal rows; z==2 -> write V transposed
// MODE 2 (PV):     fp32 out = acc * (1/rowsum[row])
// 256 threads = 4 waves, 128x128 tile, BK=64, 16x16x32 bf16 MFMA.
// ---------------------------------------------------------------------------
template <int MODE>
__global__ __launch_bounds__(256, 4) void gemm_bt(
    const unsigned short* __restrict__ Ab, const unsigned short* __restrict__ Bb,
    unsigned short* __restrict__ Cb, float* __restrict__ Cf,
    unsigned short* __restrict__ VT,
    const float* __restrict__ bias0, const float* __restrict__ bias1,
    const float* __restrict__ bias2, float* __restrict__ rowsum,
    int K, int N, float scale, long sA, long sB, long sC) {
  __shared__ unsigned short As[128 * 64];
  __shared__ unsigned short Bs[128 * 64];

  const int z = blockIdx.z;
  const unsigned short* A  = Ab + (long)z * sA;
  const unsigned short* Bm = Bb + (long)z * sB;

  const int tid  = threadIdx.x;
  const int lane = tid & 63;
  const int wave = tid >> 6;
  const int l15  = lane & 15;
  const int quad = lane >> 4;
  const int wm = (wave >> 1) * 64;
  const int wn = (wave & 1) * 64;

  // --- 8x8 super-tile swizzle for L2 locality ---
  const int bxd  = gridDim.x;
  const int flat = blockIdx.y * bxd + blockIdx.x;
  const int st = flat >> 6;
  const int inside = flat & 63;
  const int nstx = bxd >> 3;
  const int stx = st % nstx;
  const int sty = st / nstx;
  const int tile_m = (stx * 8 + (inside & 7)) * 128;
  const int tile_n = (sty * 8 + (inside >> 3)) * 128;

  const int rs8 = lane >> 3;
  const int kc  = (lane & 7) ^ rs8;
  const long lK = (long)K;
  const unsigned short* gA0 = A  + (long)(tile_m + wave * 32 + rs8) * lK + kc * 8;
  const unsigned short* gB0 = Bm + (long)(tile_n + wave * 32 + rs8) * lK + kc * 8;
  unsigned short* lA = &As[(wave * 32) * 64];
  unsigned short* lB = &Bs[(wave * 32) * 64];

  const int g0 = (0 * 4 + quad) ^ (l15 & 7);
  const int g1 = (1 * 4 + quad) ^ (l15 & 7);

  f32x4 acc[4][4] = {};

  for (int k0 = 0; k0 < K; k0 += 64) {
    __syncthreads();
#pragma unroll
    for (int t = 0; t < 4; ++t) {
      async_copy16(gA0 + (long)t * 8 * lK + k0, lA + t * 8 * 64);
      async_copy16(gB0 + (long)t * 8 * lK + k0, lB + t * 8 * 64);
    }
    __syncthreads();

#pragma unroll
    for (int s = 0; s < 2; ++s) {
      const int gs = s ? g1 : g0;
      bf16x8 af[4], bfr[4];
#pragma unroll
      for (int i = 0; i < 4; ++i)
        af[i] = *(const bf16x8*)&As[(wm + i * 16 + l15) * 64 + gs * 8];
#pragma unroll
      for (int j = 0; j < 4; ++j)
        bfr[j] = *(const bf16x8*)&Bs[(wn + j * 16 + l15) * 64 + gs * 8];
#pragma unroll
      for (int i = 0; i < 4; ++i)
#pragma unroll
        for (int j = 0; j < 4; ++j)
          acc[i][j] = __builtin_amdgcn_mfma_f32_16x16x32_bf16(af[i], bfr[j], acc[i][j], 0, 0, 0);
    }
  }

  // ------------------------- epilogue -------------------------
  if constexpr (MODE == 0) {
    const float* bias = (z == 0) ? bias0 : (z == 1) ? bias1 : bias2;
    if (z == 2) {
#pragma unroll
      for (int j = 0; j < 4; ++j) {
        const int col = tile_n + wn + j * 16 + l15;
        const float bv = bias[col];
#pragma unroll
        for (int i = 0; i < 4; ++i) {
          const int row0 = tile_m + wm + i * 16 + quad * 4;
          const int b = row0 >> 11;
          const int sx = row0 & 2047;
          ushort4 o;
          o.x = f2bf(acc[i][j][0] + bv);
          o.y = f2bf(acc[i][j][1] + bv);
          o.z = f2bf(acc[i][j][2] + bv);
          o.w = f2bf(acc[i][j][3] + bv);
          *(ushort4*)&VT[(long)b * 1024 * 2048 + (long)col * 2048 + sx] = o;
        }
      }
    } else {
      unsigned short* Cbz = Cb + (long)z * sC;
#pragma unroll
      for (int j = 0; j < 4; ++j) {
        const int col = tile_n + wn + j * 16 + l15;
        const float bv = bias[col];
#pragma unroll
        for (int i = 0; i < 4; ++i) {
          const int row0 = tile_m + wm + i * 16 + quad * 4;
#pragma unroll
          for (int r = 0; r < 4; ++r)
            Cbz[(long)(row0 + r) * N + col] = f2bf(acc[i][j][r] + bv);
        }
      }
    }
  } else {
    float* Cfz = Cf + (long)z * sC;
    float inv[16];
#pragma unroll
    for (int i = 0; i < 4; ++i) {
      const int row0 = tile_m + wm + i * 16 + quad * 4;
#pragma unroll
      for (int r = 0; r < 4; ++r)
        inv[i * 4 + r] = 1.0f / rowsum[z * 2048 + row0 + r];
    }
#pragma unroll
    for (int j = 0; j < 4; ++j) {
      const int col = tile_n + wn + j * 16 + l15;
#pragma unroll
      for (int i = 0; i < 4; ++i) {
        const int row0 = tile_m + wm + i * 16 + quad * 4;
#pragma unroll
        for (int r = 0; r < 4; ++r)
          Cfz[(long)(row0 + r) * N + col] = acc[i][j][r] * inv[i * 4 + r];
      }
    }
  }
}

// ---------------------------------------------------------------------------
// SCORES, half-tile-ring 8-wave kernel.  P = exp(Q K^T / 32), + row sums.
// 256x256 tile, BK=64, per-wave C = 256 rows x 32 cols (waves = col strips).
// LDS: As[2][2half][128x64], Bs same = 128 KiB.  Per K-tile: 4 phases,
// phase p: A-frags f=4p..4p+3 (8 ds_read_b128; A-half p>>1 -> progressive),
// B (4 reads) at p0 only, resident.  Stage 1 half/phase:
//   p0:(t+1,B-h1)  p1:(t+1,A-h1)  p2:(t+2,A-h0)  p3:(t+2,B-h0)
// Region-free proof: halves of buf c are read only in phases {0,1} (B, A-h0)
// or {2,3} (A-h1); stages into buf c target halves already barrier-freed.
// ONE vm_wait<4> per tile (end of p3): tile t+1 fully landed, t+2's 2 halves
// stay in flight.  Cover >= 3.5 phases per half.
// ---------------------------------------------------------------------------
__global__ __launch_bounds__(512, 2) void scores_8ph(
    const unsigned short* __restrict__ Qb, const unsigned short* __restrict__ Kb,
    unsigned short* __restrict__ P, float* __restrict__ rowsum) {
  constexpr int NT = 16;            // K = 1024 = 16 x 64
  constexpr long SE = 2048L * 1024;
  constexpr float SC = 1.0f / 32.0f;

  __shared__ unsigned short As[2][2][128 * 64];
  __shared__ unsigned short Bs[2][2][128 * 64];

  const int z = blockIdx.z;
  const unsigned short* A  = Qb + (long)z * SE;
  const unsigned short* Bm = Kb + (long)z * SE;
  const int tile_m = blockIdx.x * 256;
  const int tile_n = blockIdx.y * 256;

  const int tid  = threadIdx.x;
  const int lane = tid & 63;
  const int wave = tid >> 6;         // 0..7 = column strip
  const int l15  = lane & 15;
  const int quad = lane >> 4;

  // staging map: per half (128 rows x 64 k), wave w covers rows w*16..+16
  // via 2 instrs of 8 rows; lane L -> row +(L>>3), LDS granule L&7 holds
  // global chunk (L&7)^(L>>3)  (XOR granule swizzle, 0-conflict proven).
  const int rs8 = lane >> 3;
  const int kc  = (lane & 7) ^ rs8;
  const unsigned short* gA0 = A  + (long)(tile_m + wave * 16 + rs8) * 1024 + kc * 8;
  const unsigned short* gB0 = Bm + (long)(tile_n + wave * 16 + rs8) * 1024 + kc * 8;

  auto stA = [&](int T, int h) {
    if (T < NT) {
      const int pb = T & 1, k0 = T << 6;
      async_copy16(gA0 + (long)(h * 128) * 1024 + k0,     &As[pb][h][(wave * 16) * 64]);
      async_copy16(gA0 + (long)(h * 128 + 8) * 1024 + k0, &As[pb][h][(wave * 16 + 8) * 64]);
    }
  };
  auto stB = [&](int T, int h) {
    if (T < NT) {
      const int pb = T & 1, k0 = T << 6;
      async_copy16(gB0 + (long)(h * 128) * 1024 + k0,     &Bs[pb][h][(wave * 16) * 64]);
      async_copy16(gB0 + (long)(h * 128 + 8) * 1024 + k0, &Bs[pb][h][(wave * 16 + 8) * 64]);
    }
  };

  // prologue: t0 complete + t1's A-h0,B-h0 in flight; wait t0 (4 outstanding)
  stA(0, 0); stB(0, 0); stB(0, 1); stA(0, 1);
  stA(1, 0); stB(1, 0);
  vm_wait<4>();
  wg_bar();

  f32x4 acc[16][2] = {};

  for (int t = 0; t < NT; ++t) {
    const int c = t & 1;
    bf16x8 bfr[2][2];
#pragma unroll
    for (int p = 0; p < 4; ++p) {
      // --- stage one half (ring schedule, region barrier-freed) ---
      if (p == 0)      stB(t + 1, 1);
      else if (p == 1) stA(t + 1, 1);
      else if (p == 2) stA(t + 2, 0);
      else             stB(t + 2, 0);
      // --- ds_read this phase's fragments (buf c) ---
      bf16x8 af[4][2];
#pragma unroll
      for (int ii = 0; ii < 4; ++ii) {
        const int f = p * 4 + ii;
        const int rih = (f & 7) * 16 + l15;
#pragma unroll
        for (int kk = 0; kk < 2; ++kk)
          af[ii][kk] = *(const bf16x8*)
              &As[c][f >> 3][rih * 64 + (((kk * 4 + quad) ^ (l15 & 7)) << 3)];
      }
      if (p == 0) {
#pragma unroll
        for (int j = 0; j < 2; ++j) {
          const int rih = (wave & 3) * 32 + j * 16 + l15;
#pragma unroll
          for (int kk = 0; kk < 2; ++kk)
            bfr[j][kk] = *(const bf16x8*)
                &Bs[c][wave >> 2][rih * 64 + (((kk * 4 + quad) ^ (l15 & 7)) << 3)];
        }
      }
      wg_bar();
      asm volatile("s_waitcnt lgkmcnt(0)" ::: "memory");
      __builtin_amdgcn_s_setprio(1);
#pragma unroll
      for (int ii = 0; ii < 4; ++ii)
#pragma unroll
        for (int j = 0; j < 2; ++j)
#pragma unroll
          for (int kk = 0; kk < 2; ++kk)
            acc[p * 4 + ii][j] = __builtin_amdgcn_mfma_f32_16x16x32_bf16(
                af[ii][kk], bfr[j][kk], acc[p * 4 + ii][j], 0, 0, 0);
      __builtin_amdgcn_s_setprio(0);
      if (p == 3) {
        if (t + 2 < NT)      vm_wait<4>();  // t+1 landed; t+2 halves in flight
        else if (t + 1 < NT) vm_wait<0>();  // tail: drain last tile
      }
      wg_bar();
    }
  }

  // --- epilogue: exp + row sums.  col = tile_n + wave*32 + j*16 + l15;
  //     row = tile_m + f*16 + quad*4 + r  (m89-verified C/D layout) ---
  unsigned short* Pz = P + (long)z * (2048L * 2048);
#pragma unroll
  for (int f = 0; f < 16; ++f) {
    float pr[4] = {0.f, 0.f, 0.f, 0.f};
    const int row0 = tile_m + f * 16 + quad * 4;
#pragma unroll
    for (int j = 0; j < 2; ++j) {
      const int col = tile_n + wave * 32 + j * 16 + l15;
#pragma unroll
      for (int r = 0; r < 4; ++r) {
        const float e = __expf(acc[f][j][r] * SC);
        pr[r] += e;
        Pz[(long)(row0 + r) * 2048 + col] = f2bf(e);
      }
    }
#pragma unroll
    for (int r = 0; r < 4; ++r)
#pragma unroll
      for (int o = 1; o < 16; o <<= 1)
        pr[r] += __shfl_xor(pr[r], o);
    if (l15 == 0) {
#pragma unroll
      for (int r = 0; r < 4; ++r)
        atomicAdd(&rowsum[z * 2048 + row0 + r], pr[r]);
    }
  }
}

// ---------------------------------------------------------------------------
extern "C" void kernel_launch(void* const* d_in, const int* in_sizes, int n_in,
                              void* d_out, int out_size, void* d_ws, size_t ws_size,
                              hipStream_t stream) {
  const float* x  = (const float*)d_in[0];
  const float* Wq = (const float*)d_in[1];
  const float* bq = (const float*)d_in[2];
  const float* Wk = (const float*)d_in[3];
  const float* bk = (const float*)d_in[4];
  const float* Wv = (const float*)d_in[5];
  const float* bv = (const float*)d_in[6];
  float* out = (float*)d_out;

  constexpr int Bt = 4, S = 2048, E = 1024;
  constexpr int M = Bt * S;  // 8192

  // ws layout (bf16): x_bf | W_bf(3) | Q | K | VT | P(exp scores) | rowsum(f32)
  unsigned short* xb = (unsigned short*)d_ws;
  unsigned short* Wb = xb + (size_t)M * E;
  unsigned short* Q  = Wb + (size_t)3 * E * E;
  unsigned short* Kb = Q + (size_t)M * E;
  unsigned short* VT = Kb + (size_t)M * E;
  unsigned short* P  = VT + (size_t)M * E;
  float* rowsum = (float*)(P + (size_t)Bt * S * S);

  // 1) converts + rowsum zeroing (one launch)
  const int conv_blocks = (M * E / 4 + 3 * (E * E / 4)) / 256 + 1;
  convert_all<<<dim3(conv_blocks), dim3(256), 0, stream>>>(x, Wq, Wk, Wv, xb, Wb, rowsum);

  // 2) projections: z in {Q,K,V}; y = x W^T + b; V written transposed
  gemm_bt<0><<<dim3(M / 128, E / 128, 3), dim3(256), 0, stream>>>(
      xb, Wb, Q, nullptr, VT, bq, bk, bv, nullptr, E, E, 1.0f,
      0L, (long)E * E, (long)M * E);

  // 3) P = exp(Q K^T / 32) (unnormalized) + row sums  [8-phase ring kernel]
  scores_8ph<<<dim3(S / 256, S / 256, Bt), dim3(512), 0, stream>>>(
      Q, Kb, P, rowsum);

  // 4) out = (P V) / rowsum   (fp32 out)
  gemm_bt<2><<<dim3(S / 128, E / 128, Bt), dim3(256), 0, stream>>>(
      P, VT, nullptr, out, nullptr, nullptr, nullptr, nullptr, rowsum,
      S, E, 1.0f, (long)S * S, (long)E * S, (long)S * E);
}

// Round 6
// 253.714 us; speedup vs baseline: 1.3026x; 1.0370x over previous
//
#include <hip/hip_runtime.h>
#include <cstdint>

// ---------------------------------------------------------------------------
// AttentionModel: out = softmax((xWq^T+bq)(xWk^T+bk)^T / 32) (xWv^T+bv)
// B=4, S=2048, E=1024, fp32 in/out.  bf16 MFMA pipeline.
// R14: back to the R8 multi-block structure for ALL GEMMs (the only mechanism
// that measured >30% MfmaUtil here).  Lockstep phase templates are DEAD on
// this workload: R9/R10/R11/R13 all landed 17-23% util; per-phase arithmetic
// (64 ds_read_b128 ~768cyc serialized vs 155cyc MFMA per CU at 1 blk/CU)
// postdicts all four.  R12 lesson: 32x32 frags at BK=64 -> forced >=4-way LDS
// conflicts.  16x16x32 + XOR granule swizzle only.
// ONE new lever: scores+PV (cold HBM operands, P=32MB) get an intra-block
// LDS double-buffer with counted vmcnt: stage tile t+2 into the buffer freed
// by the post-compute barrier; vm_wait<8> waits only tile t+1 (issued one
// full compute-tile ago) -> ~900cyc HBM staging latency mostly hidden instead
// of fully drained by __syncthreads.  Costs 64KB LDS -> 2 blocks/CU (vs 4).
// Proj keeps the verbatim R8 path (888 TF, B L2-resident, nothing to hide).
// ---------------------------------------------------------------------------

typedef __attribute__((ext_vector_type(8))) short bf16x8;
typedef __attribute__((ext_vector_type(4))) float f32x4;

__device__ __forceinline__ unsigned short f2bf(float f) {
  union { float f; uint32_t u; } x; x.f = f;
  uint32_t u = x.u;
  return (unsigned short)((u + 0x7fffu + ((u >> 16) & 1u)) >> 16);  // RNE
}

__device__ __forceinline__ void async_copy16(const void* g, void* l) {
  __builtin_amdgcn_global_load_lds(
      (const __attribute__((address_space(1))) void*)g,
      (__attribute__((address_space(3))) void*)l, 16, 0, 0);
}

#define FENCE() asm volatile("" ::: "memory")

__device__ __forceinline__ void wg_bar() {
  FENCE();
  __builtin_amdgcn_s_barrier();
  FENCE();
}

template <int N>
__device__ __forceinline__ void vm_wait() {
  if constexpr (N == 0)      asm volatile("s_waitcnt vmcnt(0)" ::: "memory");
  else if constexpr (N == 8) asm volatile("s_waitcnt vmcnt(8)" ::: "memory");
  else                       asm volatile("s_waitcnt vmcnt(4)" ::: "memory");
}

// ---------------------------------------------------------------------------
// Merged fp32->bf16 convert for x, Wq, Wk, Wv; last block zeroes rowsum.
// ---------------------------------------------------------------------------
__global__ __launch_bounds__(256) void convert_all(
    const float* __restrict__ x, const float* __restrict__ Wq,
    const float* __restrict__ Wk, const float* __restrict__ Wv,
    unsigned short* __restrict__ xb, unsigned short* __restrict__ Wb,
    float* __restrict__ rowsum) {
  const long X4 = (long)8192 * 1024 / 4;
  const long W4 = (long)1024 * 1024 / 4;
  if (blockIdx.x == gridDim.x - 1) {
    float4* r = (float4*)rowsum;
#pragma unroll
    for (int t = 0; t < 8; ++t)
      r[threadIdx.x + t * 256] = float4{0.f, 0.f, 0.f, 0.f};
    return;
  }
  long i = (long)blockIdx.x * 256 + threadIdx.x;
  const float* src; unsigned short* dst; long off;
  if (i < X4)             { src = x;  dst = xb;                    off = i; }
  else if (i < X4 + W4)   { src = Wq; dst = Wb;                    off = i - X4; }
  else if (i < X4 + 2*W4) { src = Wk; dst = Wb + (long)1024*1024;  off = i - X4 - W4; }
  else                    { src = Wv; dst = Wb + (long)2048*1024;  off = i - X4 - 2*W4; }
  const float4 v = ((const float4*)src)[off];
  ushort4 o;
  o.x = f2bf(v.x); o.y = f2bf(v.y); o.z = f2bf(v.z); o.w = f2bf(v.w);
  ((ushort4*)dst)[off] = o;
}

// ---------------------------------------------------------------------------
// C[M,N] = op( scale * (A[M,K] x B[N,K]^T) + bias )
// MODE 0 (PROJ):   bf16 out; z<2 -> normal rows; z==2 -> write V transposed
//                  DBUF=0: verbatim R8 single-buffer loop (4 blocks/CU).
// MODE 1 (SCORES): bf16 out = exp(scale*acc); atomicAdd per-row sums
// MODE 2 (PV):     fp32 out = acc * (1/rowsum[row])
//                  MODE 1/2 use DBUF=1: 2x32KB LDS ping-pong, counted vmcnt,
//                  raw s_barrier (no vmcnt(0) drain in steady state).
// 256 threads = 4 waves, 128x128 tile, BK=64, 16x16x32 bf16 MFMA.
// Block swizzle: flat id -> 8x8 super-tiles (requires grid dims % 8 == 0).
// ---------------------------------------------------------------------------
template <int MODE, int DBUF>
__global__ __launch_bounds__(256, 4) void gemm_bt(
    const unsigned short* __restrict__ Ab, const unsigned short* __restrict__ Bb,
    unsigned short* __restrict__ Cb, float* __restrict__ Cf,
    unsigned short* __restrict__ VT,
    const float* __restrict__ bias0, const float* __restrict__ bias1,
    const float* __restrict__ bias2, float* __restrict__ rowsum,
    int K, int N, float scale, long sA, long sB, long sC) {
  constexpr int NBUF = DBUF ? 2 : 1;
  __shared__ unsigned short As[NBUF][128 * 64];
  __shared__ unsigned short Bs[NBUF][128 * 64];

  const int z = blockIdx.z;
  const unsigned short* A  = Ab + (long)z * sA;
  const unsigned short* Bm = Bb + (long)z * sB;

  const int tid  = threadIdx.x;
  const int lane = tid & 63;
  const int wave = tid >> 6;
  const int l15  = lane & 15;
  const int quad = lane >> 4;
  const int wm = (wave >> 1) * 64;
  const int wn = (wave & 1) * 64;

  // --- 8x8 super-tile swizzle for L2 locality ---
  const int bxd  = gridDim.x;
  const int flat = blockIdx.y * bxd + blockIdx.x;
  const int st = flat >> 6;          // super-tile index (64 blocks each)
  const int inside = flat & 63;
  const int nstx = bxd >> 3;
  const int stx = st % nstx;
  const int sty = st / nstx;
  const int tile_m = (stx * 8 + (inside & 7)) * 128;
  const int tile_n = (sty * 8 + (inside >> 3)) * 128;

  // --- staging map: wave w covers rows [w*32, w*32+32), 4 instrs x 8 rows.
  // Lane L -> LDS slot L&7 of row strip+(L>>3); content = chunk (L&7)^(L>>3).
  const int rs8 = lane >> 3;
  const int kc  = (lane & 7) ^ rs8;
  const long lK = (long)K;
  const unsigned short* gA0 = A  + (long)(tile_m + wave * 32 + rs8) * lK + kc * 8;
  const unsigned short* gB0 = Bm + (long)(tile_n + wave * 32 + rs8) * lK + kc * 8;

  // --- fragment granule select: physical = (s*4+quad) ^ (row&7), row&7=l15&7
  const int g0 = (0 * 4 + quad) ^ (l15 & 7);
  const int g1 = (1 * 4 + quad) ^ (l15 & 7);

  f32x4 acc[4][4] = {};

  auto stage = [&](int k0, int pb) {
#pragma unroll
    for (int t = 0; t < 4; ++t) {
      async_copy16(gA0 + (long)t * 8 * lK + k0, &As[pb][(wave * 32 + t * 8) * 64]);
      async_copy16(gB0 + (long)t * 8 * lK + k0, &Bs[pb][(wave * 32 + t * 8) * 64]);
    }
  };

  auto compute = [&](int pb) {
#pragma unroll
    for (int s = 0; s < 2; ++s) {
      const int gs = s ? g1 : g0;
      bf16x8 af[4], bfr[4];
#pragma unroll
      for (int i = 0; i < 4; ++i)
        af[i] = *(const bf16x8*)&As[pb][(wm + i * 16 + l15) * 64 + gs * 8];
#pragma unroll
      for (int j = 0; j < 4; ++j)
        bfr[j] = *(const bf16x8*)&Bs[pb][(wn + j * 16 + l15) * 64 + gs * 8];
#pragma unroll
      for (int i = 0; i < 4; ++i)
#pragma unroll
        for (int j = 0; j < 4; ++j)
          acc[i][j] = __builtin_amdgcn_mfma_f32_16x16x32_bf16(af[i], bfr[j], acc[i][j], 0, 0, 0);
    }
  };

  if constexpr (DBUF == 0) {
    // verbatim R8 loop: 4 blocks/CU, cross-block TLP hides the drain
    for (int k0 = 0; k0 < K; k0 += 64) {
      __syncthreads();  // previous-iter LDS readers done
      stage(k0, 0);
      __syncthreads();  // drain: LDS tile ready
      compute(0);
    }
  } else {
    // dbuf ping-pong with counted vmcnt: tile t+1 always fully in flight
    // during compute(t); stage(t+2) issued into the buffer freed by the
    // post-compute barrier.  vm_wait<8> waits t+1 (16 outstanding -> 8).
    const int NT = K >> 6;   // >= 16 for all our shapes
    stage(0, 0);
    stage(64, 1);
    vm_wait<8>();
    wg_bar();
    for (int t = 0; t < NT; ++t) {
      const int p = t & 1;
      compute(p);
      wg_bar();                       // all waves done reading buf p
      if (t + 2 < NT) {
        stage((t + 2) << 6, p);       // refill freed buffer
        vm_wait<8>();                 // t+1 landed; t+2 stays in flight
        wg_bar();
      } else if (t + 1 < NT) {
        vm_wait<0>();                 // tail: drain last tile
        wg_bar();
      }
    }
  }

  // ------------------------- epilogue -------------------------
  // C/D layout: col = lane&15, row = quad*4 + reg (m89-verified)
  if constexpr (MODE == 0) {
    const float* bias = (z == 0) ? bias0 : (z == 1) ? bias1 : bias2;
    if (z == 2) {
      // write V transposed: VT[b][f][s], b = row>>11, s = row&2047
#pragma unroll
      for (int j = 0; j < 4; ++j) {
        const int col = tile_n + wn + j * 16 + l15;  // feature f
        const float bv = bias[col];
#pragma unroll
        for (int i = 0; i < 4; ++i) {
          const int row0 = tile_m + wm + i * 16 + quad * 4;  // token
          const int b = row0 >> 11;
          const int sx = row0 & 2047;
          ushort4 o;
          o.x = f2bf(acc[i][j][0] + bv);
          o.y = f2bf(acc[i][j][1] + bv);
          o.z = f2bf(acc[i][j][2] + bv);
          o.w = f2bf(acc[i][j][3] + bv);
          *(ushort4*)&VT[(long)b * 1024 * 2048 + (long)col * 2048 + sx] = o;
        }
      }
    } else {
      unsigned short* Cbz = Cb + (long)z * sC;
#pragma unroll
      for (int j = 0; j < 4; ++j) {
        const int col = tile_n + wn + j * 16 + l15;
        const float bv = bias[col];
#pragma unroll
        for (int i = 0; i < 4; ++i) {
          const int row0 = tile_m + wm + i * 16 + quad * 4;
#pragma unroll
          for (int r = 0; r < 4; ++r)
            Cbz[(long)(row0 + r) * N + col] = f2bf(acc[i][j][r] + bv);
        }
      }
    }
  } else if constexpr (MODE == 1) {
    // exp epilogue + row-sum atomics
    unsigned short* Cbz = Cb + (long)z * sC;
    float part[16];
#pragma unroll
    for (int t = 0; t < 16; ++t) part[t] = 0.0f;
#pragma unroll
    for (int j = 0; j < 4; ++j) {
      const int col = tile_n + wn + j * 16 + l15;
#pragma unroll
      for (int i = 0; i < 4; ++i) {
        const int row0 = tile_m + wm + i * 16 + quad * 4;
#pragma unroll
        for (int r = 0; r < 4; ++r) {
          const float e = __expf(acc[i][j][r] * scale);
          part[i * 4 + r] += e;
          Cbz[(long)(row0 + r) * N + col] = f2bf(e);
        }
      }
    }
    // reduce across the 16 lanes (l15) sharing each row
#pragma unroll
    for (int t = 0; t < 16; ++t)
#pragma unroll
      for (int o = 1; o < 16; o <<= 1)
        part[t] += __shfl_xor(part[t], o);
    if (l15 == 0) {
#pragma unroll
      for (int i = 0; i < 4; ++i) {
        const int row0 = tile_m + wm + i * 16 + quad * 4;
#pragma unroll
        for (int r = 0; r < 4; ++r)
          atomicAdd(&rowsum[z * 2048 + row0 + r], part[i * 4 + r]);
      }
    }
  } else {
    // PV: normalize by rowsum
    float* Cfz = Cf + (long)z * sC;
    float inv[16];
#pragma unroll
    for (int i = 0; i < 4; ++i) {
      const int row0 = tile_m + wm + i * 16 + quad * 4;
#pragma unroll
      for (int r = 0; r < 4; ++r)
        inv[i * 4 + r] = 1.0f / rowsum[z * 2048 + row0 + r];
    }
#pragma unroll
    for (int j = 0; j < 4; ++j) {
      const int col = tile_n + wn + j * 16 + l15;
#pragma unroll
      for (int i = 0; i < 4; ++i) {
        const int row0 = tile_m + wm + i * 16 + quad * 4;
#pragma unroll
        for (int r = 0; r < 4; ++r)
          Cfz[(long)(row0 + r) * N + col] = acc[i][j][r] * inv[i * 4 + r];
      }
    }
  }
}

// ---------------------------------------------------------------------------
extern "C" void kernel_launch(void* const* d_in, const int* in_sizes, int n_in,
                              void* d_out, int out_size, void* d_ws, size_t ws_size,
                              hipStream_t stream) {
  const float* x  = (const float*)d_in[0];
  const float* Wq = (const float*)d_in[1];
  const float* bq = (const float*)d_in[2];
  const float* Wk = (const float*)d_in[3];
  const float* bk = (const float*)d_in[4];
  const float* Wv = (const float*)d_in[5];
  const float* bv = (const float*)d_in[6];
  float* out = (float*)d_out;

  constexpr int Bt = 4, S = 2048, E = 1024;
  constexpr int M = Bt * S;  // 8192

  // ws layout (bf16): x_bf | W_bf(3) | Q | K | VT | P(exp scores) | rowsum(f32)
  unsigned short* xb = (unsigned short*)d_ws;
  unsigned short* Wb = xb + (size_t)M * E;
  unsigned short* Q  = Wb + (size_t)3 * E * E;
  unsigned short* Kb = Q + (size_t)M * E;
  unsigned short* VT = Kb + (size_t)M * E;
  unsigned short* P  = VT + (size_t)M * E;
  float* rowsum = (float*)(P + (size_t)Bt * S * S);

  // 1) converts + rowsum zeroing (one launch)
  const int conv_blocks = (M * E / 4 + 3 * (E * E / 4)) / 256 + 1;
  convert_all<<<dim3(conv_blocks), dim3(256), 0, stream>>>(x, Wq, Wk, Wv, xb, Wb, rowsum);

  // 2) projections: z in {Q,K,V}; y = x W^T + b; V written transposed
  //    R8-verbatim single-buffer path (4 blocks/CU)
  gemm_bt<0, 0><<<dim3(M / 128, E / 128, 3), dim3(256), 0, stream>>>(
      xb, Wb, Q, nullptr, VT, bq, bk, bv, nullptr, E, E, 1.0f,
      0L, (long)E * E, (long)M * E);

  // 3) P = exp(Q K^T / 32) (unnormalized) + row sums   [dbuf counted vmcnt]
  gemm_bt<1, 1><<<dim3(S / 128, S / 128, Bt), dim3(256), 0, stream>>>(
      Q, Kb, P, nullptr, nullptr, nullptr, nullptr, nullptr, rowsum,
      E, S, 1.0f / 32.0f, (long)S * E, (long)S * E, (long)S * S);

  // 4) out = (P V) / rowsum   (fp32 out)                [dbuf counted vmcnt]
  gemm_bt<2, 1><<<dim3(S / 128, E / 128, Bt), dim3(256), 0, stream>>>(
      P, VT, nullptr, out, nullptr, nullptr, nullptr, nullptr, rowsum,
      S, E, 1.0f, (long)S * S, (long)E * S, (long)S * E);
}

// Round 7
// 239.308 us; speedup vs baseline: 1.3810x; 1.0602x over previous
//
#include <hip/hip_runtime.h>
#include <cstdint>

// ---------------------------------------------------------------------------
// AttentionModel: out = softmax((xWq^T+bq)(xWk^T+bk)^T / 32) (xWv^T+bv)
// B=4, S=2048, E=1024, fp32 in/out.  bf16 MFMA pipeline.
// R15 = R14 with STATIC dbuf indexing.  R14's counters: VALUBusy 23->36.6%
// (runtime pb=t&1 made all 64 ds_read + 8 stage LDS addresses per-iteration
// VALU recomputes; R8's static buffer let them hoist).  Fix: unroll the tile
// loop in pairs with LITERAL buffer indices; NT is 16/32 (even).  Keep the
// counted vmcnt pipeline (tile t+1 fully in flight during compute(t); vmcnt
// drained to 0 only at the tail).  Proj remains on the DBUF=0 R8 path
// (L2-resident staging, 4 blocks/CU) as the control.
// Session ledger: lockstep phase templates dead (R9/R10/R11/R13: 17-23%
// util, per-phase serialization arithmetic postdicts all four).  32x32 MFMA
// frags at BK=64 dead (R12: forced >=4-way LDS conflicts).  16x16x32 + XOR
// granule swizzle + multi-block TLP is the proven mechanism.
// ---------------------------------------------------------------------------

typedef __attribute__((ext_vector_type(8))) short bf16x8;
typedef __attribute__((ext_vector_type(4))) float f32x4;

__device__ __forceinline__ unsigned short f2bf(float f) {
  union { float f; uint32_t u; } x; x.f = f;
  uint32_t u = x.u;
  return (unsigned short)((u + 0x7fffu + ((u >> 16) & 1u)) >> 16);  // RNE
}

__device__ __forceinline__ void async_copy16(const void* g, void* l) {
  __builtin_amdgcn_global_load_lds(
      (const __attribute__((address_space(1))) void*)g,
      (__attribute__((address_space(3))) void*)l, 16, 0, 0);
}

#define FENCE() asm volatile("" ::: "memory")

__device__ __forceinline__ void wg_bar() {
  FENCE();
  __builtin_amdgcn_s_barrier();
  FENCE();
}

template <int N>
__device__ __forceinline__ void vm_wait() {
  if constexpr (N == 0)      asm volatile("s_waitcnt vmcnt(0)" ::: "memory");
  else if constexpr (N == 8) asm volatile("s_waitcnt vmcnt(8)" ::: "memory");
  else                       asm volatile("s_waitcnt vmcnt(4)" ::: "memory");
}

// ---------------------------------------------------------------------------
// Merged fp32->bf16 convert for x, Wq, Wk, Wv; last block zeroes rowsum.
// ---------------------------------------------------------------------------
__global__ __launch_bounds__(256) void convert_all(
    const float* __restrict__ x, const float* __restrict__ Wq,
    const float* __restrict__ Wk, const float* __restrict__ Wv,
    unsigned short* __restrict__ xb, unsigned short* __restrict__ Wb,
    float* __restrict__ rowsum) {
  const long X4 = (long)8192 * 1024 / 4;
  const long W4 = (long)1024 * 1024 / 4;
  if (blockIdx.x == gridDim.x - 1) {
    float4* r = (float4*)rowsum;
#pragma unroll
    for (int t = 0; t < 8; ++t)
      r[threadIdx.x + t * 256] = float4{0.f, 0.f, 0.f, 0.f};
    return;
  }
  long i = (long)blockIdx.x * 256 + threadIdx.x;
  const float* src; unsigned short* dst; long off;
  if (i < X4)             { src = x;  dst = xb;                    off = i; }
  else if (i < X4 + W4)   { src = Wq; dst = Wb;                    off = i - X4; }
  else if (i < X4 + 2*W4) { src = Wk; dst = Wb + (long)1024*1024;  off = i - X4 - W4; }
  else                    { src = Wv; dst = Wb + (long)2048*1024;  off = i - X4 - 2*W4; }
  const float4 v = ((const float4*)src)[off];
  ushort4 o;
  o.x = f2bf(v.x); o.y = f2bf(v.y); o.z = f2bf(v.z); o.w = f2bf(v.w);
  ((ushort4*)dst)[off] = o;
}

// ---------------------------------------------------------------------------
// C[M,N] = op( scale * (A[M,K] x B[N,K]^T) + bias )
// MODE 0 (PROJ):   bf16 out; z<2 -> normal rows; z==2 -> write V transposed
//                  DBUF=0: verbatim R8 single-buffer loop (4 blocks/CU).
// MODE 1 (SCORES): bf16 out = exp(scale*acc); atomicAdd per-row sums
// MODE 2 (PV):     fp32 out = acc * (1/rowsum[row])
//                  MODE 1/2 use DBUF=1: 2x32KB LDS ping-pong with LITERAL
//                  buffer indices (pair-unrolled loop), counted vmcnt, raw
//                  s_barrier (no vmcnt(0) drain in steady state).
// 256 threads = 4 waves, 128x128 tile, BK=64, 16x16x32 bf16 MFMA.
// Block swizzle: flat id -> 8x8 super-tiles (requires grid dims % 8 == 0).
// ---------------------------------------------------------------------------
template <int MODE, int DBUF>
__global__ __launch_bounds__(256, 4) void gemm_bt(
    const unsigned short* __restrict__ Ab, const unsigned short* __restrict__ Bb,
    unsigned short* __restrict__ Cb, float* __restrict__ Cf,
    unsigned short* __restrict__ VT,
    const float* __restrict__ bias0, const float* __restrict__ bias1,
    const float* __restrict__ bias2, float* __restrict__ rowsum,
    int K, int N, float scale, long sA, long sB, long sC) {
  constexpr int NBUF = DBUF ? 2 : 1;
  __shared__ unsigned short As[NBUF][128 * 64];
  __shared__ unsigned short Bs[NBUF][128 * 64];

  const int z = blockIdx.z;
  const unsigned short* A  = Ab + (long)z * sA;
  const unsigned short* Bm = Bb + (long)z * sB;

  const int tid  = threadIdx.x;
  const int lane = tid & 63;
  const int wave = tid >> 6;
  const int l15  = lane & 15;
  const int quad = lane >> 4;
  const int wm = (wave >> 1) * 64;
  const int wn = (wave & 1) * 64;

  // --- 8x8 super-tile swizzle for L2 locality ---
  const int bxd  = gridDim.x;
  const int flat = blockIdx.y * bxd + blockIdx.x;
  const int st = flat >> 6;          // super-tile index (64 blocks each)
  const int inside = flat & 63;
  const int nstx = bxd >> 3;
  const int stx = st % nstx;
  const int sty = st / nstx;
  const int tile_m = (stx * 8 + (inside & 7)) * 128;
  const int tile_n = (sty * 8 + (inside >> 3)) * 128;

  // --- staging map: wave w covers rows [w*32, w*32+32), 4 instrs x 8 rows.
  // Lane L -> LDS slot L&7 of row strip+(L>>3); content = chunk (L&7)^(L>>3).
  const int rs8 = lane >> 3;
  const int kc  = (lane & 7) ^ rs8;
  const long lK = (long)K;
  const unsigned short* gA0 = A  + (long)(tile_m + wave * 32 + rs8) * lK + kc * 8;
  const unsigned short* gB0 = Bm + (long)(tile_n + wave * 32 + rs8) * lK + kc * 8;

  // --- fragment granule select: physical = (s*4+quad) ^ (row&7), row&7=l15&7
  const int g0 = (0 * 4 + quad) ^ (l15 & 7);
  const int g1 = (1 * 4 + quad) ^ (l15 & 7);

  f32x4 acc[4][4] = {};

  // pb is always a LITERAL at every call site -> all LDS addresses fold to
  // compile-time constants (R14 lesson: runtime pb cost +14pts VALUBusy).
  auto stage = [&](int k0, int pb) {
#pragma unroll
    for (int t = 0; t < 4; ++t) {
      async_copy16(gA0 + (long)t * 8 * lK + k0, &As[pb][(wave * 32 + t * 8) * 64]);
      async_copy16(gB0 + (long)t * 8 * lK + k0, &Bs[pb][(wave * 32 + t * 8) * 64]);
    }
  };

  auto compute = [&](int pb) {
#pragma unroll
    for (int s = 0; s < 2; ++s) {
      const int gs = s ? g1 : g0;
      bf16x8 af[4], bfr[4];
#pragma unroll
      for (int i = 0; i < 4; ++i)
        af[i] = *(const bf16x8*)&As[pb][(wm + i * 16 + l15) * 64 + gs * 8];
#pragma unroll
      for (int j = 0; j < 4; ++j)
        bfr[j] = *(const bf16x8*)&Bs[pb][(wn + j * 16 + l15) * 64 + gs * 8];
#pragma unroll
      for (int i = 0; i < 4; ++i)
#pragma unroll
        for (int j = 0; j < 4; ++j)
          acc[i][j] = __builtin_amdgcn_mfma_f32_16x16x32_bf16(af[i], bfr[j], acc[i][j], 0, 0, 0);
    }
  };

  if constexpr (DBUF == 0) {
    // verbatim R8 loop: 4 blocks/CU, cross-block TLP hides the drain
    for (int k0 = 0; k0 < K; k0 += 64) {
      __syncthreads();  // previous-iter LDS readers done
      stage(k0, 0);
      __syncthreads();  // drain: LDS tile ready
      compute(0);
    }
  } else {
    // static ping-pong, pair-unrolled.  Invariant: at compute(b) of tile t,
    // tile t landed at the immediately preceding vm_wait<8> (8 = the one
    // still-in-flight stage of 8 loads).  vmcnt(0) only at the tail.
    const int NT = K >> 6;   // 16 or 32 (even) for all our shapes
    stage(0, 0);
    stage(64, 1);
    vm_wait<8>();            // tile 0 landed; tile 1 in flight
    wg_bar();
    for (int t = 0; t < NT; t += 2) {
      compute(0);                       // tile t
      wg_bar();                         // all waves done reading buf 0
      if (t + 2 < NT) { stage((t + 2) << 6, 0); vm_wait<8>(); }  // t+1 landed
      else            { vm_wait<0>(); }                          // drain t+1
      wg_bar();
      compute(1);                       // tile t+1
      wg_bar();                         // all waves done reading buf 1
      if (t + 3 < NT)      { stage((t + 3) << 6, 1); vm_wait<8>(); }
      else if (t + 2 < NT) { vm_wait<0>(); }
      wg_bar();
    }
  }

  // ------------------------- epilogue -------------------------
  // C/D layout: col = lane&15, row = quad*4 + reg (m89-verified)
  if constexpr (MODE == 0) {
    const float* bias = (z == 0) ? bias0 : (z == 1) ? bias1 : bias2;
    if (z == 2) {
      // write V transposed: VT[b][f][s], b = row>>11, s = row&2047
#pragma unroll
      for (int j = 0; j < 4; ++j) {
        const int col = tile_n + wn + j * 16 + l15;  // feature f
        const float bv = bias[col];
#pragma unroll
        for (int i = 0; i < 4; ++i) {
          const int row0 = tile_m + wm + i * 16 + quad * 4;  // token
          const int b = row0 >> 11;
          const int sx = row0 & 2047;
          ushort4 o;
          o.x = f2bf(acc[i][j][0] + bv);
          o.y = f2bf(acc[i][j][1] + bv);
          o.z = f2bf(acc[i][j][2] + bv);
          o.w = f2bf(acc[i][j][3] + bv);
          *(ushort4*)&VT[(long)b * 1024 * 2048 + (long)col * 2048 + sx] = o;
        }
      }
    } else {
      unsigned short* Cbz = Cb + (long)z * sC;
#pragma unroll
      for (int j = 0; j < 4; ++j) {
        const int col = tile_n + wn + j * 16 + l15;
        const float bv = bias[col];
#pragma unroll
        for (int i = 0; i < 4; ++i) {
          const int row0 = tile_m + wm + i * 16 + quad * 4;
#pragma unroll
          for (int r = 0; r < 4; ++r)
            Cbz[(long)(row0 + r) * N + col] = f2bf(acc[i][j][r] + bv);
        }
      }
    }
  } else if constexpr (MODE == 1) {
    // exp epilogue + row-sum atomics
    unsigned short* Cbz = Cb + (long)z * sC;
    float part[16];
#pragma unroll
    for (int t = 0; t < 16; ++t) part[t] = 0.0f;
#pragma unroll
    for (int j = 0; j < 4; ++j) {
      const int col = tile_n + wn + j * 16 + l15;
#pragma unroll
      for (int i = 0; i < 4; ++i) {
        const int row0 = tile_m + wm + i * 16 + quad * 4;
#pragma unroll
        for (int r = 0; r < 4; ++r) {
          const float e = __expf(acc[i][j][r] * scale);
          part[i * 4 + r] += e;
          Cbz[(long)(row0 + r) * N + col] = f2bf(e);
        }
      }
    }
    // reduce across the 16 lanes (l15) sharing each row
#pragma unroll
    for (int t = 0; t < 16; ++t)
#pragma unroll
      for (int o = 1; o < 16; o <<= 1)
        part[t] += __shfl_xor(part[t], o);
    if (l15 == 0) {
#pragma unroll
      for (int i = 0; i < 4; ++i) {
        const int row0 = tile_m + wm + i * 16 + quad * 4;
#pragma unroll
        for (int r = 0; r < 4; ++r)
          atomicAdd(&rowsum[z * 2048 + row0 + r], part[i * 4 + r]);
      }
    }
  } else {
    // PV: normalize by rowsum
    float* Cfz = Cf + (long)z * sC;
    float inv[16];
#pragma unroll
    for (int i = 0; i < 4; ++i) {
      const int row0 = tile_m + wm + i * 16 + quad * 4;
#pragma unroll
      for (int r = 0; r < 4; ++r)
        inv[i * 4 + r] = 1.0f / rowsum[z * 2048 + row0 + r];
    }
#pragma unroll
    for (int j = 0; j < 4; ++j) {
      const int col = tile_n + wn + j * 16 + l15;
#pragma unroll
      for (int i = 0; i < 4; ++i) {
        const int row0 = tile_m + wm + i * 16 + quad * 4;
#pragma unroll
        for (int r = 0; r < 4; ++r)
          Cfz[(long)(row0 + r) * N + col] = acc[i][j][r] * inv[i * 4 + r];
      }
    }
  }
}

// ---------------------------------------------------------------------------
extern "C" void kernel_launch(void* const* d_in, const int* in_sizes, int n_in,
                              void* d_out, int out_size, void* d_ws, size_t ws_size,
                              hipStream_t stream) {
  const float* x  = (const float*)d_in[0];
  const float* Wq = (const float*)d_in[1];
  const float* bq = (const float*)d_in[2];
  const float* Wk = (const float*)d_in[3];
  const float* bk = (const float*)d_in[4];
  const float* Wv = (const float*)d_in[5];
  const float* bv = (const float*)d_in[6];
  float* out = (float*)d_out;

  constexpr int Bt = 4, S = 2048, E = 1024;
  constexpr int M = Bt * S;  // 8192

  // ws layout (bf16): x_bf | W_bf(3) | Q | K | VT | P(exp scores) | rowsum(f32)
  unsigned short* xb = (unsigned short*)d_ws;
  unsigned short* Wb = xb + (size_t)M * E;
  unsigned short* Q  = Wb + (size_t)3 * E * E;
  unsigned short* Kb = Q + (size_t)M * E;
  unsigned short* VT = Kb + (size_t)M * E;
  unsigned short* P  = VT + (size_t)M * E;
  float* rowsum = (float*)(P + (size_t)Bt * S * S);

  // 1) converts + rowsum zeroing (one launch)
  const int conv_blocks = (M * E / 4 + 3 * (E * E / 4)) / 256 + 1;
  convert_all<<<dim3(conv_blocks), dim3(256), 0, stream>>>(x, Wq, Wk, Wv, xb, Wb, rowsum);

  // 2) projections: z in {Q,K,V}; y = x W^T + b; V written transposed
  //    R8-verbatim single-buffer path (4 blocks/CU)
  gemm_bt<0, 0><<<dim3(M / 128, E / 128, 3), dim3(256), 0, stream>>>(
      xb, Wb, Q, nullptr, VT, bq, bk, bv, nullptr, E, E, 1.0f,
      0L, (long)E * E, (long)M * E);

  // 3) P = exp(Q K^T / 32) (unnormalized) + row sums   [static dbuf]
  gemm_bt<1, 1><<<dim3(S / 128, S / 128, Bt), dim3(256), 0, stream>>>(
      Q, Kb, P, nullptr, nullptr, nullptr, nullptr, nullptr, rowsum,
      E, S, 1.0f / 32.0f, (long)S * E, (long)S * E, (long)S * S);

  // 4) out = (P V) / rowsum   (fp32 out)                [static dbuf]
  gemm_bt<2, 1><<<dim3(S / 128, E / 128, Bt), dim3(256), 0, stream>>>(
      P, VT, nullptr, out, nullptr, nullptr, nullptr, nullptr, rowsum,
      S, E, 1.0f, (long)S * S, (long)E * S, (long)S * E);
}